// Round 1
// baseline (829.292 us; speedup 1.0000x reference)
//
#include <hip/hip_runtime.h>

#define S 2048
#define HID 2048
#define NH 16
#define DH 128
#define VOC 128
#define QK_SCALE 0.08838834764831845f

typedef __bf16 bf16_t;
typedef __attribute__((ext_vector_type(8))) __bf16 bf16x8;
typedef __attribute__((ext_vector_type(4))) __bf16 bf16x4;
typedef __attribute__((ext_vector_type(4))) float f32x4;

typedef __attribute__((address_space(1))) unsigned int guint;
typedef __attribute__((address_space(3))) unsigned int luint;

__device__ __forceinline__ void gl_lds16(const void* g, void* l) {
  __builtin_amdgcn_global_load_lds((guint*)(unsigned long long)g,
                                   (luint*)(unsigned)(unsigned long long)l,
                                   16, 0, 0);
}

// ---------------- mask precompute ----------------
// mi[i] = {flags = nonpad | spec<<1 | segb<<2, wint, sint, 0}
__global__ __launch_bounds__(256) void mask_prep(const int* __restrict__ tokens,
                                                 const unsigned char* __restrict__ seg,
                                                 const unsigned char* __restrict__ spc,
                                                 int4* __restrict__ mi) {
  __shared__ int ssp[257], ssg[257];
  __shared__ int slay;
  int t = threadIdx.x;
  if (t == 0) {
    // detect bool-array layout: 1-byte bool, int32, or float32
    int nz = 0, f32c = 0;
    for (int i = 0; i < 256; i++) {
      if ((i & 3) != 0 && seg[i]) nz++;
      if ((i & 3) == 3 && seg[i] == 0x3f) f32c++;   // 1.0f high byte
    }
    slay = (f32c > 8) ? 2 : ((nz > 4) ? 1 : 0);
  }
  __syncthreads();
  int lay = slay;
  auto getb = [&](const unsigned char* p, int i) -> int {
    if (lay == 1) return p[i] != 0;
    if (lay == 2) return ((const float*)p)[i] != 0.f;
    return ((const int*)p)[i] != 0;
  };
  int base = t * 8, a = 0, b = 0;
  for (int j = 0; j < 8; j++) { a += getb(spc, base + j); b += 1 - getb(seg, base + j); }
  ssp[t + 1] = a; ssg[t + 1] = b;
  __syncthreads();
  if (t == 0) {
    ssp[0] = 0; ssg[0] = 0;
    for (int i = 1; i <= 256; i++) { ssp[i] += ssp[i - 1]; ssg[i] += ssg[i - 1]; }
  }
  __syncthreads();
  int esp = ssp[t], esg = ssg[t];   // exclusive prefixes at element base
  for (int j = 0; j < 8; j++) {
    int i = base + j;
    int sp = getb(spc, i), sg = 1 - getb(seg, i);
    int np = (tokens[i] != 127) ? 1 : 0;
    int wint = (i == 0) ? (1 + sp) : (1 + esp);
    int sint = (i == 0) ? (1 + sg) : (1 + esg);
    mi[i] = make_int4(np | (sp << 1) | (sg << 2), wint, sint, 0);
    esp += sp; esg += sg;
  }
}

// ---------------- embedding gather ----------------
__global__ __launch_bounds__(256) void embed_k(const int* __restrict__ tokens,
                                               const float* __restrict__ emb,
                                               float* __restrict__ h) {
  int row = blockIdx.x;
  int tok = tokens[row];
  const float4* src = (const float4*)(emb + (size_t)tok * HID);
  float4* dst = (float4*)(h + (size_t)row * HID);
  for (int i = threadIdx.x; i < HID / 4; i += 256) dst[i] = src[i];
}

// ---------------- f32 -> bf16 (+ transposed copy) ----------------
__global__ __launch_bounds__(256) void cvtT(const float* __restrict__ h,
                                            bf16_t* __restrict__ hb,
                                            bf16_t* __restrict__ hbT) {
  __shared__ bf16_t tile[64][65];
  int t = threadIdx.x;
  int r = t >> 2;            // 0..63
  int cq = (t & 3) * 16;     // 0,16,32,48
  int row = blockIdx.x * 64 + r;
  int col0 = blockIdx.y * 64 + cq;
  const float* src = h + (size_t)row * HID + col0;
  bf16x8 va, vb;
  {
    float4 f0 = *(const float4*)(src);
    float4 f1 = *(const float4*)(src + 4);
    float4 f2 = *(const float4*)(src + 8);
    float4 f3 = *(const float4*)(src + 12);
    va[0] = (bf16_t)f0.x; va[1] = (bf16_t)f0.y; va[2] = (bf16_t)f0.z; va[3] = (bf16_t)f0.w;
    va[4] = (bf16_t)f1.x; va[5] = (bf16_t)f1.y; va[6] = (bf16_t)f1.z; va[7] = (bf16_t)f1.w;
    vb[0] = (bf16_t)f2.x; vb[1] = (bf16_t)f2.y; vb[2] = (bf16_t)f2.z; vb[3] = (bf16_t)f2.w;
    vb[4] = (bf16_t)f3.x; vb[5] = (bf16_t)f3.y; vb[6] = (bf16_t)f3.z; vb[7] = (bf16_t)f3.w;
  }
  *(bf16x8*)(hb + (size_t)row * HID + col0) = va;
  *(bf16x8*)(hb + (size_t)row * HID + col0 + 8) = vb;
  #pragma unroll
  for (int i = 0; i < 8; i++) { tile[r][cq + i] = va[i]; tile[r][cq + 8 + i] = vb[i]; }
  __syncthreads();
  bf16x8 ta, tb;
  #pragma unroll
  for (int i = 0; i < 8; i++) { ta[i] = tile[cq + i][r]; tb[i] = tile[cq + 8 + i][r]; }
  bf16_t* dstT = hbT + (size_t)(blockIdx.y * 64 + r) * S + blockIdx.x * 64 + cq;
  *(bf16x8*)dstT = ta;
  *(bf16x8*)(dstT + 8) = tb;
}

// ---------------- fused masked attention (one layer) ----------------
__device__ __forceinline__ bool mpair(const int4& qi, const int4& ki) {
  if (!((qi.x & ki.x) & 1)) return false;                    // nonpad q & kv
  if (!((ki.x >> 1) & 1) && (qi.y != ki.y)) return false;    // word mask
  if (!((ki.x >> 2) & 1) && (qi.z != ki.z)) return false;    // segment mask
  return true;
}

__global__ __launch_bounds__(256) void attn_kern(const bf16_t* __restrict__ hbf,
                                                 const bf16_t* __restrict__ hbfT,
                                                 const int4* __restrict__ mi,
                                                 float* __restrict__ out) {
  __shared__ bf16_t Kl[32 * 128];   // K tile [32 kv][128 d], 16B chunks XOR-swizzled by row&7
  __shared__ bf16_t Vt[128 * 32];   // V^T tile [128 d][32 kv], linear
  __shared__ bf16_t Pl[4][640];     // per-wave P tile [16 q][32 kv], row stride 40 halves

  int h = blockIdx.x;
  int qb = (int)gridDim.y - 1 - (int)blockIdx.y;   // big blocks dispatch first
  int tid = threadIdx.x;
  int w = tid >> 6, l = tid & 63, l16 = l & 15, g = l >> 4;
  int q0 = qb * 64 + w * 16;

  // Q fragments: A[row=l16][k=8g+j] per 32-wide k-step
  bf16x8 qf[4];
  {
    const bf16_t* qrow = hbf + (size_t)(q0 + l16) * HID + h * DH;
    #pragma unroll
    for (int ks = 0; ks < 4; ks++) qf[ks] = *(const bf16x8*)(qrow + ks * 32 + g * 8);
  }
  int4 miq[4];
  #pragma unroll
  for (int r = 0; r < 4; r++) miq[r] = mi[q0 + 4 * g + r];

  float m[4] = {-1e30f, -1e30f, -1e30f, -1e30f};
  float lsum[4] = {0.f, 0.f, 0.f, 0.f};
  f32x4 acc[8];
  #pragma unroll
  for (int d = 0; d < 8; d++) acc[d] = (f32x4){0.f, 0.f, 0.f, 0.f};

  int T = qb * 2 + 2;            // kv tiles of 32 covering kv <= q0_block+63
  for (int t = 0; t < T; t++) {
    int kv0 = t * 32;
    __syncthreads();
    // stage K (pre-swizzled source -> linear LDS dest)
    #pragma unroll
    for (int i = 0; i < 2; i++) {
      int seg = w * 2 + i;
      int row = seg * 4 + (l >> 4);
      int ch = l16 ^ (row & 7);
      gl_lds16(hbf + (size_t)(kv0 + row) * HID + h * DH + ch * 8, &Kl[seg * 512]);
    }
    // stage V^T (linear)
    #pragma unroll
    for (int i = 0; i < 2; i++) {
      int seg = w * 2 + i;
      int row = seg * 16 + (l >> 2);
      int ch = l & 3;
      gl_lds16(hbfT + (size_t)(h * DH + row) * S + kv0 + ch * 8, &Vt[seg * 512]);
    }
    __syncthreads();

    // QK^T: two 16x16 column tiles
    f32x4 sacc[2];
    #pragma unroll
    for (int c = 0; c < 2; c++) {
      f32x4 a = (f32x4){0.f, 0.f, 0.f, 0.f};
      int krow = 16 * c + l16;
      const bf16_t* kr = &Kl[krow * 128];
      int swz = krow & 7;
      #pragma unroll
      for (int ks = 0; ks < 4; ks++) {
        int ch = (4 * ks + g) ^ swz;
        bf16x8 kf = *(const bf16x8*)(kr + ch * 8);
        a = __builtin_amdgcn_mfma_f32_16x16x32_bf16(qf[ks], kf, a, 0, 0, 0);
      }
      sacc[c] = a;
    }

    int kvA = kv0 + l16, kvB = kv0 + 16 + l16;
    int4 miA = mi[kvA], miB = mi[kvB];
    float pf0[4], pf1[4];
    #pragma unroll
    for (int r = 0; r < 4; r++) {
      int q = q0 + 4 * g + r;
      float sA = sacc[0][r] * QK_SCALE, sB = sacc[1][r] * QK_SCALE;
      bool vA = (kvA <= q) && mpair(miq[r], miA);
      bool vB = (kvB <= q) && mpair(miq[r], miB);
      sA = vA ? sA : -1e30f;
      sB = vB ? sB : -1e30f;
      float mx = fmaxf(sA, sB);
      mx = fmaxf(mx, __shfl_xor(mx, 1, 64));
      mx = fmaxf(mx, __shfl_xor(mx, 2, 64));
      mx = fmaxf(mx, __shfl_xor(mx, 4, 64));
      mx = fmaxf(mx, __shfl_xor(mx, 8, 64));
      float mn = fmaxf(m[r], mx);
      float al = __expf(m[r] - mn);
      float pA = vA ? __expf(sA - mn) : 0.f;
      float pB = vB ? __expf(sB - mn) : 0.f;
      float ps = pA + pB;
      ps += __shfl_xor(ps, 1, 64);
      ps += __shfl_xor(ps, 2, 64);
      ps += __shfl_xor(ps, 4, 64);
      ps += __shfl_xor(ps, 8, 64);
      lsum[r] = lsum[r] * al + ps;
      m[r] = mn;
      #pragma unroll
      for (int dt = 0; dt < 8; dt++) acc[dt][r] *= al;
      pf0[r] = pA; pf1[r] = pB;
    }

    // P: D-layout -> A-layout via per-wave LDS tile
    bf16_t* pw = &Pl[w][0];
    #pragma unroll
    for (int r = 0; r < 4; r++) {
      int qr = 4 * g + r;
      pw[qr * 40 + l16] = (bf16_t)pf0[r];
      pw[qr * 40 + 16 + l16] = (bf16_t)pf1[r];
    }
    __asm__ volatile("s_waitcnt lgkmcnt(0)" ::: "memory");
    bf16x8 pa = *(const bf16x8*)(&Pl[w][l16 * 40 + g * 8]);

    // PV: 8 d-tiles of 16
    #pragma unroll
    for (int dt = 0; dt < 8; dt++) {
      bf16x8 vf = *(const bf16x8*)(&Vt[(dt * 16 + l16) * 32 + g * 8]);
      acc[dt] = __builtin_amdgcn_mfma_f32_16x16x32_bf16(pa, vf, acc[dt], 0, 0, 0);
    }
  }

  #pragma unroll
  for (int r = 0; r < 4; r++) {
    float inv = (lsum[r] > 0.f) ? 1.f / lsum[r] : 0.f;
    int q = q0 + 4 * g + r;
    float* orow = out + (size_t)q * HID + h * DH;
    #pragma unroll
    for (int dt = 0; dt < 8; dt++) orow[dt * 16 + l16] = acc[dt][r] * inv;
  }
}

// ---------------- lm head (MFMA) ----------------
__global__ __launch_bounds__(256) void wcvt(const float* __restrict__ w, bf16_t* __restrict__ wb) {
  int i = blockIdx.x * 256 + threadIdx.x;      // float4 index
  float4 f = ((const float4*)w)[i];
  bf16x4 v;
  v[0] = (bf16_t)f.x; v[1] = (bf16_t)f.y; v[2] = (bf16_t)f.z; v[3] = (bf16_t)f.w;
  *(bf16x4*)(wb + (size_t)i * 4) = v;
}

__global__ __launch_bounds__(256) void lm_head(const bf16_t* __restrict__ hbf,
                                               const bf16_t* __restrict__ wbf,
                                               const float* __restrict__ bias,
                                               float* __restrict__ out) {
  int tid = threadIdx.x;
  int w = tid >> 6, l = tid & 63, l16 = l & 15, g = l >> 4;
  int t0 = blockIdx.x * 64 + w * 16;
  f32x4 acc[8];
  #pragma unroll
  for (int i = 0; i < 8; i++) acc[i] = (f32x4){0.f, 0.f, 0.f, 0.f};
  const bf16_t* arow = hbf + (size_t)(t0 + l16) * HID;
  for (int k0 = 0; k0 < HID; k0 += 32) {
    bf16x8 af = *(const bf16x8*)(arow + k0 + g * 8);
    #pragma unroll
    for (int vt = 0; vt < 8; vt++) {
      bf16x8 bf_ = *(const bf16x8*)(wbf + (size_t)(vt * 16 + l16) * HID + k0 + g * 8);
      acc[vt] = __builtin_amdgcn_mfma_f32_16x16x32_bf16(af, bf_, acc[vt], 0, 0, 0);
    }
  }
  #pragma unroll
  for (int vt = 0; vt < 8; vt++) {
    #pragma unroll
    for (int r = 0; r < 4; r++) {
      int tok = t0 + 4 * g + r, v = vt * 16 + l16;
      out[(size_t)tok * VOC + v] = acc[vt][r] + bias[v];
    }
  }
}

// ---------------- segment head (f32 vector) ----------------
__global__ __launch_bounds__(256) void seg_head(const float* __restrict__ h,
                                                const float* __restrict__ sw,
                                                const float* __restrict__ sb,
                                                float* __restrict__ out) {
  int tok = blockIdx.x * 256 + threadIdx.x;
  const float4* hr = (const float4*)(h + (size_t)tok * HID);
  const float4* w0 = (const float4*)sw;
  const float4* w1 = (const float4*)(sw + HID);
  float a0 = 0.f, a1 = 0.f;
  for (int i = 0; i < HID / 4; i++) {
    float4 hv = hr[i], x = w0[i], y = w1[i];
    a0 += hv.x * x.x + hv.y * x.y + hv.z * x.z + hv.w * x.w;
    a1 += hv.x * y.x + hv.y * y.y + hv.z * y.z + hv.w * y.w;
  }
  out[(size_t)tok * 2] = a0 + sb[0];
  out[(size_t)tok * 2 + 1] = a1 + sb[1];
}

extern "C" void kernel_launch(void* const* d_in, const int* in_sizes, int n_in,
                              void* d_out, int out_size, void* d_ws, size_t ws_size,
                              hipStream_t stream) {
  const int* tokens = (const int*)d_in[0];
  const unsigned char* seg = (const unsigned char*)d_in[1];
  const unsigned char* spc = (const unsigned char*)d_in[2];
  const float* emb_w = (const float*)d_in[3];
  const float* lm_w = (const float*)d_in[4];
  const float* lm_b = (const float*)d_in[5];
  const float* seg_w = (const float*)d_in[6];
  const float* seg_b = (const float*)d_in[7];

  char* ws = (char*)d_ws;
  int4* mi = (int4*)ws;                                       // 32KB
  float* hA = (float*)(ws + (1u << 16));                      // 16MB
  float* hB = (float*)(ws + (1u << 16) + (16u << 20));        // 16MB
  bf16_t* hbf = (bf16_t*)(ws + (1u << 16) + (32u << 20));     // 8MB
  bf16_t* hbfT = (bf16_t*)(ws + (1u << 16) + (40u << 20));    // 8MB
  bf16_t* wbf = (bf16_t*)(ws + (1u << 16) + (48u << 20));     // 512KB
  float* out = (float*)d_out;

  mask_prep<<<1, 256, 0, stream>>>(tokens, seg, spc, mi);
  embed_k<<<S, 256, 0, stream>>>(tokens, emb_w, hA);
  float* cur = hA;
  float* nxt = hB;
  for (int L = 0; L < 4; L++) {
    cvtT<<<dim3(S / 64, HID / 64), 256, 0, stream>>>(cur, hbf, hbfT);
    attn_kern<<<dim3(NH, S / 64), 256, 0, stream>>>(hbf, hbfT, mi, nxt);
    float* tmp = cur; cur = nxt; nxt = tmp;
  }
  cvtT<<<dim3(S / 64, HID / 64), 256, 0, stream>>>(cur, hbf, hbfT);
  wcvt<<<(VOC * HID / 4) / 256, 256, 0, stream>>>(lm_w, wbf);
  lm_head<<<S / 64, 256, 0, stream>>>(hbf, wbf, lm_b, out);
  seg_head<<<S / 256, 256, 0, stream>>>(cur, seg_w, seg_b, out + (size_t)S * VOC);
}

// Round 2
// 316.740 us; speedup vs baseline: 2.6182x; 2.6182x over previous
//
#include <hip/hip_runtime.h>

#define S 2048
#define HID 2048
#define NH 16
#define DH 128
#define VOC 128
#define K2EXP 0.12752551286084112f   // (1/sqrt(128)) * log2(e)
#define RTHR 62.0f                   // defer-max threshold in raw-score units (~8 in exp2 units)
#define NEGS -3.0e38f

typedef __bf16 bf16_t;
typedef __attribute__((ext_vector_type(8))) __bf16 bf16x8;
typedef __attribute__((ext_vector_type(4))) __bf16 bf16x4;
typedef __attribute__((ext_vector_type(4))) float f32x4;

typedef __attribute__((address_space(1))) unsigned int guint;
typedef __attribute__((address_space(3))) unsigned int luint;

#define MFMA __builtin_amdgcn_mfma_f32_16x16x32_bf16

__device__ __forceinline__ void gl_lds16(const void* g, void* l) {
  __builtin_amdgcn_global_load_lds((guint*)(unsigned long long)g,
                                   (luint*)(unsigned)(unsigned long long)l,
                                   16, 0, 0);
}

// ---------------- mask interval precompute ----------------
__global__ __launch_bounds__(256) void mask_prep(const int* __restrict__ tokens,
                                                 const unsigned char* __restrict__ seg,
                                                 const unsigned char* __restrict__ spc,
                                                 int4* __restrict__ mi) {
  __shared__ int ssp[257], ssg[257];
  __shared__ int slay;
  int t = threadIdx.x;
  if (t == 0) {
    int nz = 0, f32c = 0;
    for (int i = 0; i < 256; i++) {
      if ((i & 3) != 0 && seg[i]) nz++;
      if ((i & 3) == 3 && seg[i] == 0x3f) f32c++;
    }
    slay = (f32c > 8) ? 2 : ((nz > 4) ? 1 : 0);
  }
  __syncthreads();
  int lay = slay;
  auto getb = [&](const unsigned char* p, int i) -> int {
    if (lay == 1) return p[i] != 0;
    if (lay == 2) return ((const float*)p)[i] != 0.f;
    return ((const int*)p)[i] != 0;
  };
  int base = t * 8, a = 0, b = 0;
  for (int j = 0; j < 8; j++) { a += getb(spc, base + j); b += 1 - getb(seg, base + j); }
  ssp[t + 1] = a; ssg[t + 1] = b;
  __syncthreads();
  if (t == 0) {
    ssp[0] = 0; ssg[0] = 0;
    for (int i = 1; i <= 256; i++) { ssp[i] += ssp[i - 1]; ssg[i] += ssg[i - 1]; }
  }
  __syncthreads();
  int esp = ssp[t], esg = ssg[t];
  for (int j = 0; j < 8; j++) {
    int i = base + j;
    int sp = getb(spc, i), sg = 1 - getb(seg, i);
    int np = (tokens[i] != 127) ? 1 : 0;
    int wint = (i == 0) ? (1 + sp) : (1 + esp);
    int sint = (i == 0) ? (1 + sg) : (1 + esg);
    mi[i] = make_int4(np | (sp << 1) | (sg << 2), wint, sint, 0);
    esp += sp; esg += sg;
  }
}

// ---------------- full mask bit table: cmask[word][q], word=kv/32 ----------------
__global__ __launch_bounds__(256) void bitgen(const int4* __restrict__ mi,
                                              unsigned* __restrict__ cmask) {
  __shared__ int4 km[32];
  int w = blockIdx.x;                 // kv word 0..63
  int t = threadIdx.x;
  int q = blockIdx.y * 256 + t;
  if (t < 32) km[t] = mi[w * 32 + t];
  __syncthreads();
  int4 mq = mi[q];
  unsigned word = 0;
  #pragma unroll
  for (int j = 0; j < 32; j++) {
    int kv = w * 32 + j;
    int4 mk = km[j];
    bool v = ((mq.x & mk.x) & 1) &&
             ((mk.x & 2) || (mq.y == mk.y)) &&
             ((mk.x & 4) || (mq.z == mk.z)) &&
             (kv <= q);
    word |= (v ? 1u : 0u) << j;
  }
  cmask[(size_t)w * S + q] = word;
}

// ---------------- shared transpose-store helper ----------------
__device__ __forceinline__ void store_h_hT(bf16x8 ob[4], bf16_t* tile, int q0, int h,
                                           int ql, int d0, int tid,
                                           bf16_t* __restrict__ hb, bf16_t* __restrict__ hbT) {
  #pragma unroll
  for (int i = 0; i < 4; i++)
    *(bf16x8*)(hb + (size_t)(q0 + ql) * HID + h * DH + d0 + i * 8) = ob[i];
  #pragma unroll
  for (int i = 0; i < 4; i++)
    #pragma unroll
    for (int j = 0; j < 8; j++) tile[ql * 136 + d0 + i * 8 + j] = ob[i][j];
  __syncthreads();
  int dT = tid >> 1, qh = (tid & 1) * 32;
  bf16x8 tb[4];
  #pragma unroll
  for (int i = 0; i < 4; i++)
    #pragma unroll
    for (int j = 0; j < 8; j++) tb[i][j] = tile[(qh + i * 8 + j) * 136 + dT];
  #pragma unroll
  for (int i = 0; i < 4; i++)
    *(bf16x8*)(hbT + (size_t)(h * DH + dT) * S + q0 + qh + i * 8) = tb[i];
}

// ---------------- embedding gather -> bf16 h and h^T ----------------
__global__ __launch_bounds__(256) void embedT(const int* __restrict__ tokens,
                                              const float* __restrict__ emb,
                                              bf16_t* __restrict__ hb, bf16_t* __restrict__ hbT) {
  __shared__ bf16_t tile[64 * 136];
  int tid = threadIdx.x;
  int q0 = blockIdx.x * 64, h = blockIdx.y;
  int ql = tid >> 2, d0 = (tid & 3) * 32;
  int tok = tokens[q0 + ql];
  const float4* src = (const float4*)(emb + (size_t)tok * HID + h * DH + d0);
  bf16x8 ob[4];
  #pragma unroll
  for (int i = 0; i < 8; i++) {
    float4 f = src[i];
    ob[i >> 1][(i & 1) * 4 + 0] = (bf16_t)f.x;
    ob[i >> 1][(i & 1) * 4 + 1] = (bf16_t)f.y;
    ob[i >> 1][(i & 1) * 4 + 2] = (bf16_t)f.z;
    ob[i >> 1][(i & 1) * 4 + 3] = (bf16_t)f.w;
  }
  store_h_hT(ob, tile, q0, h, ql, d0, tid, hb, hbT);
}

// ---------------- combine partials -> bf16 h and h^T ----------------
__global__ __launch_bounds__(256) void combine_k(const bf16_t* __restrict__ OP,
                                                 const float2* __restrict__ ml,
                                                 bf16_t* __restrict__ hb, bf16_t* __restrict__ hbT) {
  __shared__ bf16_t tile[64 * 136];
  int tid = threadIdx.x;
  int q0 = blockIdx.x * 64, h = blockIdx.y;
  int ql = tid >> 2, d0 = (tid & 3) * 32;
  int q = q0 + ql;
  float2 a = ml[(size_t)h * S + q];
  float2 b = ml[(size_t)(16 + h) * S + q];
  float M = fmaxf(a.x, b.x);
  float c1 = exp2f((a.x - M) * K2EXP), c2 = exp2f((b.x - M) * K2EXP);
  float lt = a.y * c1 + b.y * c2;
  float inv = lt > 0.f ? 1.f / lt : 0.f;
  c1 *= inv; c2 *= inv;
  const bf16x8* o1 = (const bf16x8*)(OP + ((size_t)h * S + q) * DH + d0);
  const bf16x8* o2 = (const bf16x8*)(OP + ((size_t)(16 + h) * S + q) * DH + d0);
  bf16x8 ob[4];
  #pragma unroll
  for (int i = 0; i < 4; i++) {
    bf16x8 x = o1[i], y = o2[i];
    #pragma unroll
    for (int j = 0; j < 8; j++)
      ob[i][j] = (bf16_t)((float)x[j] * c1 + (float)y[j] * c2);
  }
  store_h_hT(ob, tile, q0, h, ql, d0, tid, hb, hbT);
}

// ---------------- attention partial (kv-split flash, swapped QK^T) ----------------
__device__ __forceinline__ void online_sm(f32x4 s[4], unsigned w0, unsigned w1, int g, int l16,
                                          float& m, float& lsum, f32x4 (&acc)[8],
                                          bf16_t* prow) {
  float sv[16];
  #pragma unroll
  for (int c = 0; c < 4; c++) {
    unsigned wd = (c < 2) ? w0 : w1;
    #pragma unroll
    for (int r = 0; r < 4; r++) {
      unsigned bit = (wd >> (16 * (c & 1) + 4 * g + r)) & 1u;
      sv[c * 4 + r] = bit ? s[c][r] : NEGS;
    }
  }
  float mx = sv[0];
  #pragma unroll
  for (int i = 1; i < 16; i++) mx = fmaxf(mx, sv[i]);
  mx = fmaxf(mx, __shfl_xor(mx, 16, 64));
  mx = fmaxf(mx, __shfl_xor(mx, 32, 64));
  if (__any(mx > m + RTHR)) {
    float mn = fmaxf(m, mx);
    float al = exp2f((m - mn) * K2EXP);
    m = mn; lsum *= al;
    #pragma unroll
    for (int r = 0; r < 4; r++) {
      float alr = __shfl(al, 4 * g + r, 64);
      #pragma unroll
      for (int dt = 0; dt < 8; dt++) acc[dt][r] *= alr;
    }
  }
  float mk = m * K2EXP;
  float p[16];
  float ps = 0.f;
  #pragma unroll
  for (int i = 0; i < 16; i++) p[i] = exp2f(sv[i] * K2EXP - mk);
  #pragma unroll
  for (int i = 0; i < 16; i++) ps += p[i];
  ps += __shfl_xor(ps, 16, 64);
  ps += __shfl_xor(ps, 32, 64);
  lsum += ps;
  #pragma unroll
  for (int c = 0; c < 4; c++) {
    bf16x4 pk;
    #pragma unroll
    for (int r = 0; r < 4; r++) pk[r] = (bf16_t)p[c * 4 + r];
    *(bf16x4*)(prow + l16 * 72 + 16 * c + 4 * g) = pk;
  }
}

__global__ __launch_bounds__(256, 2) void attn_part(const bf16_t* __restrict__ hb,
                                                    const bf16_t* __restrict__ hbT,
                                                    const unsigned* __restrict__ cmask,
                                                    bf16_t* __restrict__ OP,
                                                    float2* __restrict__ ml) {
  __shared__ bf16_t Kl[64 * 128];     // K tile [64 kv][128 d], chunks XOR-swizzled
  __shared__ bf16_t Vt[128 * 64];     // V^T tile [128 d][64 kv], chunks XOR-swizzled
  __shared__ bf16_t Pl[4 * 32 * 72];  // per-wave P [32 q][64 kv] stride 72

  int h = blockIdx.x, qb = blockIdx.y, sp = blockIdx.z;
  int tid = threadIdx.x, w = tid >> 6, l = tid & 63, l16 = l & 15, g = l >> 4;
  int qbh = 31 - qb;
  int q0l = qb * 64 + w * 16, q0h = qbh * 64 + w * 16;

  bf16x8 qfl[4], qfh[4];
  #pragma unroll
  for (int ks = 0; ks < 4; ks++) {
    qfl[ks] = *(const bf16x8*)(hb + (size_t)(q0l + l16) * HID + h * DH + ks * 32 + g * 8);
    qfh[ks] = *(const bf16x8*)(hb + (size_t)(q0h + l16) * HID + h * DH + ks * 32 + g * 8);
  }
  float mL = -1e30f, lL = 0.f, mH = -1e30f, lH = 0.f;
  f32x4 aL[8], aH[8];
  #pragma unroll
  for (int i = 0; i < 8; i++) { aL[i] = (f32x4){0.f,0.f,0.f,0.f}; aH[i] = (f32x4){0.f,0.f,0.f,0.f}; }
  bf16_t* Pw = Pl + w * (32 * 72);

  for (int t = sp; t <= qbh; t += 2) {
    int kv0 = t * 64;
    bool alo = (t <= qb);
    __syncthreads();
    // stage K[64x128] and V^T[128x64] (pre-swizzled global source, linear LDS dest)
    #pragma unroll
    for (int i = 0; i < 4; i++) {
      int s = w * 4 + i;
      { int row = s * 4 + (l >> 4); int ch = (l & 15) ^ (row & 7);
        gl_lds16(hb + (size_t)(kv0 + row) * HID + h * DH + ch * 8, Kl + s * 512); }
      { int row = s * 8 + (l >> 3); int ch = (l & 7) ^ (row & 7);
        gl_lds16(hbT + (size_t)(h * DH + row) * S + kv0 + ch * 8, Vt + s * 512); }
    }
    int cw = kv0 >> 5;
    unsigned wl0 = 0, wl1 = 0;
    if (alo) { wl0 = cmask[(size_t)cw * S + q0l + l16]; wl1 = cmask[(size_t)(cw + 1) * S + q0l + l16]; }
    unsigned wh0 = cmask[(size_t)cw * S + q0h + l16];
    unsigned wh1 = cmask[(size_t)(cw + 1) * S + q0h + l16];
    __syncthreads();

    // QK^T swapped: S^T[kv][q] = K x Q^T ; K-frags shared across lo/hi
    f32x4 sL[4], sH[4];
    #pragma unroll
    for (int c = 0; c < 4; c++) { sL[c] = (f32x4){0.f,0.f,0.f,0.f}; sH[c] = (f32x4){0.f,0.f,0.f,0.f}; }
    int swz = l16 & 7;
    #pragma unroll
    for (int c = 0; c < 4; c++) {
      const bf16_t* kr = Kl + (16 * c + l16) * 128;
      #pragma unroll
      for (int ks = 0; ks < 4; ks++) {
        bf16x8 kf = *(const bf16x8*)(kr + 8 * ((4 * ks + g) ^ swz));
        if (alo) sL[c] = MFMA(kf, qfl[ks], sL[c], 0, 0, 0);
        sH[c] = MFMA(kf, qfh[ks], sH[c], 0, 0, 0);
      }
    }
    if (alo) online_sm(sL, wl0, wl1, g, l16, mL, lL, aL, Pw);
    online_sm(sH, wh0, wh1, g, l16, mH, lH, aH, Pw + 16 * 72);
    __asm__ volatile("s_waitcnt lgkmcnt(0)" ::: "memory");

    bf16x8 pL[2], pH[2];
    #pragma unroll
    for (int ks = 0; ks < 2; ks++) {
      if (alo) pL[ks] = *(const bf16x8*)(Pw + l16 * 72 + ks * 32 + g * 8);
      pH[ks] = *(const bf16x8*)(Pw + 16 * 72 + l16 * 72 + ks * 32 + g * 8);
    }
    #pragma unroll
    for (int dt = 0; dt < 8; dt++) {
      const bf16_t* vr = Vt + (dt * 16 + l16) * 64;
      #pragma unroll
      for (int ks = 0; ks < 2; ks++) {
        bf16x8 vf = *(const bf16x8*)(vr + 8 * ((4 * ks + g) ^ swz));
        if (alo) aL[dt] = MFMA(pL[ks], vf, aL[dt], 0, 0, 0);
        aH[dt] = MFMA(pH[ks], vf, aH[dt], 0, 0, 0);
      }
    }
  }

  // epilogue: store unnormalized partials + (m,l)
  size_t baseL = ((size_t)(sp * 16 + h) * S + q0l) * DH;
  size_t baseH = ((size_t)(sp * 16 + h) * S + q0h) * DH;
  #pragma unroll
  for (int dt = 0; dt < 8; dt++)
    #pragma unroll
    for (int r = 0; r < 4; r++) {
      OP[baseL + (size_t)(4 * g + r) * DH + dt * 16 + l16] = (bf16_t)aL[dt][r];
      OP[baseH + (size_t)(4 * g + r) * DH + dt * 16 + l16] = (bf16_t)aH[dt][r];
    }
  if (l < 16) {
    ml[(size_t)(sp * 16 + h) * S + q0l + l16] = make_float2(mL, lL);
    ml[(size_t)(sp * 16 + h) * S + q0h + l16] = make_float2(mH, lH);
  }
}

// ---------------- lm head ----------------
__global__ __launch_bounds__(256) void wcvt(const float* __restrict__ w, bf16_t* __restrict__ wb) {
  int i = blockIdx.x * 256 + threadIdx.x;
  float4 f = ((const float4*)w)[i];
  bf16x4 v;
  v[0] = (bf16_t)f.x; v[1] = (bf16_t)f.y; v[2] = (bf16_t)f.z; v[3] = (bf16_t)f.w;
  *(bf16x4*)(wb + (size_t)i * 4) = v;
}

__global__ __launch_bounds__(256) void lm_head(const bf16_t* __restrict__ hb,
                                               const bf16_t* __restrict__ wbf,
                                               const float* __restrict__ bias,
                                               float* __restrict__ out) {
  __shared__ float red[4][16][130];
  int tid = threadIdx.x;
  int w = tid >> 6, l = tid & 63, l16 = l & 15, g = l >> 4;
  int t0 = blockIdx.x * 16;
  f32x4 acc[8];
  #pragma unroll
  for (int i = 0; i < 8; i++) acc[i] = (f32x4){0.f, 0.f, 0.f, 0.f};
  const bf16_t* arow = hb + (size_t)(t0 + l16) * HID + w * 512;
  for (int k0 = 0; k0 < 512; k0 += 32) {
    bf16x8 af = *(const bf16x8*)(arow + k0 + g * 8);
    #pragma unroll
    for (int vt = 0; vt < 8; vt++) {
      bf16x8 bf_ = *(const bf16x8*)(wbf + (size_t)(vt * 16 + l16) * HID + w * 512 + k0 + g * 8);
      acc[vt] = MFMA(af, bf_, acc[vt], 0, 0, 0);
    }
  }
  #pragma unroll
  for (int vt = 0; vt < 8; vt++)
    #pragma unroll
    for (int r = 0; r < 4; r++)
      red[w][4 * g + r][vt * 16 + l16] = acc[vt][r];
  __syncthreads();
  int q = tid >> 4, vc = (tid & 15) * 8;
  #pragma unroll
  for (int j = 0; j < 8; j++) {
    float s = red[0][q][vc + j] + red[1][q][vc + j] + red[2][q][vc + j] + red[3][q][vc + j];
    out[(size_t)(t0 + q) * VOC + vc + j] = s + bias[vc + j];
  }
}

// ---------------- segment head (bf16 hidden) ----------------
__global__ __launch_bounds__(256) void seg_head(const bf16_t* __restrict__ hb,
                                                const float* __restrict__ sw,
                                                const float* __restrict__ sb,
                                                float* __restrict__ out) {
  int tid = threadIdx.x;
  int token = blockIdx.x * 8 + (tid >> 5);
  int lane = tid & 31;
  const bf16x8* hr = (const bf16x8*)(hb + (size_t)token * HID);
  const float4* w0 = (const float4*)sw;
  const float4* w1 = (const float4*)(sw + HID);
  float a0 = 0.f, a1 = 0.f;
  #pragma unroll
  for (int i = 0; i < 8; i++) {
    int c = lane + i * 32;
    bf16x8 v = hr[c];
    float4 x0 = w0[c * 2], x1 = w0[c * 2 + 1];
    float4 y0 = w1[c * 2], y1 = w1[c * 2 + 1];
    a0 += (float)v[0]*x0.x + (float)v[1]*x0.y + (float)v[2]*x0.z + (float)v[3]*x0.w
        + (float)v[4]*x1.x + (float)v[5]*x1.y + (float)v[6]*x1.z + (float)v[7]*x1.w;
    a1 += (float)v[0]*y0.x + (float)v[1]*y0.y + (float)v[2]*y0.z + (float)v[3]*y0.w
        + (float)v[4]*y1.x + (float)v[5]*y1.y + (float)v[6]*y1.z + (float)v[7]*y1.w;
  }
  #pragma unroll
  for (int off = 16; off; off >>= 1) {
    a0 += __shfl_xor(a0, off, 64);
    a1 += __shfl_xor(a1, off, 64);
  }
  if (lane == 0) {
    out[(size_t)token * 2] = a0 + sb[0];
    out[(size_t)token * 2 + 1] = a1 + sb[1];
  }
}

extern "C" void kernel_launch(void* const* d_in, const int* in_sizes, int n_in,
                              void* d_out, int out_size, void* d_ws, size_t ws_size,
                              hipStream_t stream) {
  const int* tokens = (const int*)d_in[0];
  const unsigned char* seg = (const unsigned char*)d_in[1];
  const unsigned char* spc = (const unsigned char*)d_in[2];
  const float* emb_w = (const float*)d_in[3];
  const float* lm_w = (const float*)d_in[4];
  const float* lm_b = (const float*)d_in[5];
  const float* seg_w = (const float*)d_in[6];
  const float* seg_b = (const float*)d_in[7];

  char* ws = (char*)d_ws;
  int4* mi = (int4*)ws;                                  // 32KB
  unsigned* cmask = (unsigned*)(ws + (64u << 10));       // 512KB @64KB
  bf16_t* hb  = (bf16_t*)(ws + (1u << 20));              // 8MB  @1MB
  bf16_t* hbT = (bf16_t*)(ws + (9u << 20));              // 8MB  @9MB
  bf16_t* OP  = (bf16_t*)(ws + (17u << 20));             // 16MB @17MB
  float2* ml  = (float2*)(ws + (33u << 20));             // 512KB @33MB
  bf16_t* wbf = (bf16_t*)(ws + (34u << 20));             // 512KB @34MB
  float* out = (float*)d_out;

  mask_prep<<<1, 256, 0, stream>>>(tokens, seg, spc, mi);
  bitgen<<<dim3(64, 8), 256, 0, stream>>>(mi, cmask);
  embedT<<<dim3(S / 64, NH), 256, 0, stream>>>(tokens, emb_w, hb, hbT);
  for (int L = 0; L < 4; L++) {
    attn_part<<<dim3(NH, 16, 2), 256, 0, stream>>>(hb, hbT, cmask, OP, ml);
    combine_k<<<dim3(S / 64, NH), 256, 0, stream>>>(OP, ml, hb, hbT);
  }
  wcvt<<<(VOC * HID / 4) / 256, 256, 0, stream>>>(lm_w, wbf);
  lm_head<<<S / 16, 256, 0, stream>>>(hb, wbf, lm_b, out);
  seg_head<<<S / 8, 256, 0, stream>>>(hb, seg_w, seg_b, out + (size_t)S * VOC);
}